// Round 5
// baseline (306.753 us; speedup 1.0000x reference)
//
#include <hip/hip_runtime.h>
#include <math.h>

// Attention: out = softmax((q@Wq+bq)(k@Wk+bk)^T / sqrt(D)) @ (v@Wv+bv)
// B=4, S=2048, D=1024, fp32 in/out.
//
// Round 11: geometry change (the schedule-invariant bottleneck).
// r8-r10 post-mortem: three schedules, identical ~1650cyc/phase, MfmaUtil
// ~30%. Invariants: (a) per-wave 64x64 tile -> FLOP/LDS-read-byte = 32,
// LDS pipe ~4x MFMA pipe; (b) 1 block/CU -> all waves in barrier lockstep.
// Fixes:
//   - per-wave output 128x64 (acc[8][4], 128 VGPR), 4 waves (1Mx4N),
//     256-thread blocks, block tile 128x256, BK=32 -> ratio 42.7
//   - LDS: 3 bufs x 24KB (A[128][32] + B[256][32]) = 72KB -> 2 blocks/CU
//     (cross-block read/MFMA overlap, the m114 mechanism)
//   - distance-3 prefetch, counted vmcnt(12) steady state
//   - same XOR swizzle (slot ^= (row>>1)&3), 0 bank conflicts (r7-verified)
// Schedule per K-tile t (single phase, 12 ds_read + 32 MFMA + 6 stages):
//   READ12(b0); lgkm(0); SBAR; [STAGE(b0,t+3)]; MFMA32; VMW(g); SBAR
// vmcnt ledger (6 loads/tile-group):
//   guard t+1 at end of tile t: newer groups = t+2, t+3 ->
//   12 if t+3<nt, 6 if t+2<nt<=t+3, 0 if t+1<nt<=t+2; loop exits at nt-1.
//   prologue: stage tiles 0,1,2 (18 loads); VMW(12) guards tile0.
// Overwrite hazard: STAGE(b0,t+3) issued after [lgkm(0) by all waves +
// SBAR] -> every ds_read of b0 retired before DMA writes can land. Safe.
// __launch_bounds__(256,2): VGPR cap at 8-waves/CU level (256) -- fits
// ~220 without spill (r7 lesson: (512,2) forced 108+spill).
// Kernels: prep (unchanged) -> proj8 (768) -> scores8 (512) -> pv8 (256).

using short8  = __attribute__((ext_vector_type(8))) short;
using floatx4 = __attribute__((ext_vector_type(4))) float;

// round-half-up bf16 (2 VALU; differs from RNE only on exact ties)
__device__ __forceinline__ unsigned short f2bf(float f) {
    union { float f; unsigned u; } x; x.f = f;
    return (unsigned short)((x.u + 0x8000u) >> 16);
}

__device__ __forceinline__ void gload_lds16(const unsigned short* g, unsigned short* l) {
    __builtin_amdgcn_global_load_lds(
        (const __attribute__((address_space(1))) unsigned int*)g,
        (__attribute__((address_space(3))) unsigned int*)l, 16, 0, 0);
}

#define SBAR    __builtin_amdgcn_s_barrier()
#define SCHEDB  __builtin_amdgcn_sched_barrier(0)
#define LGKM(n) asm volatile("s_waitcnt lgkmcnt(" #n ")" ::: "memory")
#define VMW(n)  asm volatile("s_waitcnt vmcnt(" #n ")" ::: "memory")

// ---------------- prep: qkv conv (blocks 0..24575) + W transpose (24576..27647) ----
__global__ __launch_bounds__(256) void prep(
    const float* __restrict__ q, const float* __restrict__ k, const float* __restrict__ v,
    const float* __restrict__ W0, const float* __restrict__ W1, const float* __restrict__ W2,
    unsigned short* __restrict__ qkvbf, unsigned short* __restrict__ Wt)
{
    __shared__ float tile[32][33];
    const int id = blockIdx.x;
    const int t  = threadIdx.x;
    if (id < 24576) {
        const int z  = id >> 13;
        const int xb = id & 8191;
        const float* x = (z == 0) ? q : (z == 1) ? k : v;
        const size_t i = ((size_t)xb * 256 + t) * 4;
        const float4 a = *(const float4*)(x + i);
        ushort4 p = { f2bf(a.x), f2bf(a.y), f2bf(a.z), f2bf(a.w) };
        *(ushort4*)(qkvbf + (size_t)z * 8192 * 1024 + i) = p;
    } else {
        const int idt = id - 24576;
        const int z  = idt >> 10;
        const int r  = idt & 1023;
        const int bx = (r & 31) * 32;
        const int by = (r >> 5) * 32;
        const float* W = (z == 0) ? W0 : (z == 1) ? W1 : W2;
        unsigned short* o = Wt + (size_t)z * 1024 * 1024;
        const int tx = t & 31;
        const int ty = (t >> 5) * 4;
        #pragma unroll
        for (int rr = 0; rr < 4; ++rr)
            tile[ty + rr][tx] = W[(size_t)(by + ty + rr) * 1024 + bx + tx];
        __syncthreads();
        #pragma unroll
        for (int rr = 0; rr < 4; ++rr)
            o[(size_t)(bx + ty + rr) * 1024 + by + tx] = f2bf(tile[tx][ty + rr]);
    }
}

// ======== 4-wave 128x256 GEMM, per-wave 128x64, BK=32, 3 LDS bufs ========
// LDS map (shorts): buf b at b*12288; A[128][32] at +0, B[256][32] at +4096.
// Swizzle: 16B slot s of row r holds global slot s ^ ((r>>1)&3).

#define STAGE(bb, tt) do { \
    _Pragma("unroll") \
    for (int p_ = 0; p_ < 2; ++p_) \
        gload_lds16(gA + (size_t)(p_ * 64 + srowA) * lda + (tt) * 32 + scol, \
                    lds + (bb) * 12288 + p_ * 2048 + t256 * 8); \
    _Pragma("unroll") \
    for (int p_ = 0; p_ < 4; ++p_) \
        gload_lds16(gB + (size_t)(p_ * 64 + srowA) * ldb + (tt) * 32 + scol, \
                    lds + (bb) * 12288 + 4096 + p_ * 2048 + t256 * 8); \
} while (0)

#define LDSA(bb, i) (*(const short8*)&lds[(bb) * 12288 + ((i) * 16 + l15) * 32 + rslot])
#define LDSB(bb, j) (*(const short8*)&lds[(bb) * 12288 + 4096 + (wv * 64 + (j) * 16 + l15) * 32 + rslot])

#define MFMA32 do { \
    __builtin_amdgcn_s_setprio(1); \
    _Pragma("unroll") \
    for (int i_ = 0; i_ < 8; ++i_) \
        _Pragma("unroll") \
        for (int j_ = 0; j_ < 4; ++j_) \
            acc[i_][j_] = __builtin_amdgcn_mfma_f32_16x16x32_bf16( \
                af[i_], bf[j_], acc[i_][j_], 0, 0, 0); \
    __builtin_amdgcn_s_setprio(0); \
} while (0)

__device__ __forceinline__ void gemm_w4(
    const unsigned short* __restrict__ gA, int lda,
    const unsigned short* __restrict__ gB, int ldb,
    int nt, unsigned short* lds, floatx4 (&acc)[8][4])
{
    const int t256 = threadIdx.x;
    const int lane = t256 & 63;
    const int wv   = t256 >> 6;          // wave 0..3 = N-position
    const int l15  = lane & 15;
    const int quad = lane >> 4;
    const int srowA = t256 >> 2;                                 // staging row 0..63 (+p*64)
    const int scol  = ((t256 & 3) ^ ((t256 >> 3) & 3)) * 8;      // pre-swizzled global slot
    const int rslot = (quad ^ ((l15 >> 1) & 3)) * 8;             // swizzled read slot

    short8 af[8], bf[4];

    // prologue: stage tiles 0,1,2 (18 loads)
    STAGE(0, 0); STAGE(1, 1); STAGE(2, 2);
    VMW(12);           // tile 0 landed (12 newer)
    SBAR;

    int b0 = 0, b1 = 1, b2 = 2;
    for (int t = 0; t < nt; ++t) {
        #pragma unroll
        for (int j = 0; j < 4; ++j) bf[j] = LDSB(b0, j);
        #pragma unroll
        for (int i = 0; i < 8; ++i) af[i] = LDSA(b0, i);
        LGKM(0); SCHEDB;          // own reads of b0 done
        SBAR;                     // ALL waves' reads of b0 done
        if (t + 3 < nt) STAGE(b0, t + 3);   // reuse just-freed buffer
        MFMA32;                   // overlaps the 6 in-flight stages
        if (t + 1 < nt) {
            if (t + 3 < nt)      { VMW(12); }   // t+2, t+3 outstanding
            else if (t + 2 < nt) { VMW(6);  }   // t+2 outstanding
            else                 { VMW(0);  }
            SBAR;
            const int tmp = b0; b0 = b1; b1 = b2; b2 = tmp;
        }
    }
}

#define EPI_IDS                                   \
    const int tt   = threadIdx.x;                 \
    const int lane = tt & 63;                     \
    const int wv   = tt >> 6;                     \
    const int l15  = lane & 15;                   \
    const int quad = lane >> 4;

// ---------------- fused QKV projection, 768 blocks, XCD-swizzled ----
__global__ __launch_bounds__(256, 2) void proj8(
    const unsigned short* __restrict__ Abf,
    const unsigned short* __restrict__ Wt,
    const float* __restrict__ bq, const float* __restrict__ bk, const float* __restrict__ bv,
    unsigned short* __restrict__ Qp, unsigned short* __restrict__ Kp,
    unsigned short* __restrict__ Vpt)
{
    __shared__ __attribute__((aligned(16))) unsigned short lds[36864];
    const int id = blockIdx.x;
    const int g  = (id & 7) * 96 + (id >> 3);    // 768 = 8 XCDs x 96
    const int z  = g >> 8;                       // 0..2
    const int r  = g & 255;
    const int m0 = (r >> 2) * 128;
    const int n0 = (r & 3) * 256;

    const unsigned short* gA = Abf + (size_t)z * 8192 * 1024 + (size_t)m0 * 1024;
    const unsigned short* gB = Wt  + (size_t)z * 1024 * 1024 + (size_t)n0 * 1024;

    floatx4 acc[8][4] = {};
    gemm_w4(gA, 1024, gB, 1024, 32, lds, acc);

    EPI_IDS
    const float* bias = (z == 0) ? bq : (z == 1) ? bk : bv;
    #pragma unroll
    for (int j = 0; j < 4; ++j) {
        const int col = n0 + wv * 64 + j * 16 + l15;
        const float bv_ = bias[col];
        #pragma unroll
        for (int i = 0; i < 8; ++i) {
            const int row = m0 + i * 16 + quad * 4;
            if (z < 2) {
                unsigned short* C = (z == 0) ? Qp : Kp;
                #pragma unroll
                for (int r2 = 0; r2 < 4; ++r2)
                    C[(size_t)(row + r2) * 1024 + col] = f2bf(acc[i][j][r2] + bv_);
            } else {
                ushort4 p = { f2bf(acc[i][j][0] + bv_), f2bf(acc[i][j][1] + bv_),
                              f2bf(acc[i][j][2] + bv_), f2bf(acc[i][j][3] + bv_) };
                *(ushort4*)&Vpt[(size_t)col * 8192 + row] = p;
            }
        }
    }
}

// ---------------- scores: Pexp = exp(Qp @ Kp^T / 32) bf16 + row sums ----
__global__ __launch_bounds__(256, 2) void scores8(
    const unsigned short* __restrict__ Qp,
    const unsigned short* __restrict__ Kp,
    unsigned short* __restrict__ Pexp,
    float* __restrict__ rowsum)
{
    __shared__ __attribute__((aligned(16))) unsigned short lds[36864];
    const int id = blockIdx.x;
    const int g  = (id & 7) * 64 + (id >> 3);    // 512 blocks
    const int z  = g >> 7;
    const int r  = g & 127;
    const int m0 = (r >> 3) * 128;
    const int n0 = (r & 7) * 256;

    const unsigned short* gA = Qp + (size_t)z * 2048 * 1024 + (size_t)m0 * 1024;
    const unsigned short* gB = Kp + (size_t)z * 2048 * 1024 + (size_t)n0 * 1024;

    floatx4 acc[8][4] = {};
    gemm_w4(gA, 1024, gB, 1024, 32, lds, acc);

    EPI_IDS
    unsigned short* P = Pexp + (size_t)z * 2048 * 2048;
    float* rs = rowsum + (size_t)z * 2048;
    #pragma unroll
    for (int i = 0; i < 8; ++i) {
        const int rowb = m0 + i * 16 + quad * 4;
        float sm[4] = {0.f, 0.f, 0.f, 0.f};
        #pragma unroll
        for (int j = 0; j < 4; ++j) {
            const int col = n0 + wv * 64 + j * 16 + l15;
            #pragma unroll
            for (int r2 = 0; r2 < 4; ++r2) {
                const float p = __expf(acc[i][j][r2] * 0.03125f);
                sm[r2] += p;
                P[(size_t)(rowb + r2) * 2048 + col] = f2bf(p);
            }
        }
        #pragma unroll
        for (int r2 = 0; r2 < 4; ++r2) {
            float s = sm[r2];
            s += __shfl_xor(s, 1);
            s += __shfl_xor(s, 2);
            s += __shfl_xor(s, 4);
            s += __shfl_xor(s, 8);
            if (l15 == 0)
                atomicAdd(&rs[rowb + r2], s);
        }
    }
}

// ---------------- PV: out = (Pexp @ Vpt^T) / rowsum, fp32 ----------------
__global__ __launch_bounds__(256, 2) void pv8(
    const unsigned short* __restrict__ Pexp,
    const unsigned short* __restrict__ Vpt,
    const float* __restrict__ rowsum,
    float* __restrict__ out)
{
    __shared__ __attribute__((aligned(16))) unsigned short lds[36864];
    const int id = blockIdx.x;
    const int g  = (id & 7) * 32 + (id >> 3);    // 256 blocks
    const int z  = g >> 6;
    const int r  = g & 63;
    const int m0 = (r >> 2) * 128;
    const int n0 = (r & 3) * 256;

    const unsigned short* gA = Pexp + (size_t)z * 2048 * 2048 + (size_t)m0 * 2048;
    const unsigned short* gB = Vpt  + (size_t)n0 * 8192 + (size_t)z * 2048;

    floatx4 acc[8][4] = {};
    gemm_w4(gA, 2048, gB, 8192, 64, lds, acc);

    EPI_IDS
    const float* rs = rowsum + (size_t)z * 2048;
    float* C = out + (size_t)z * 2048 * 1024;
    #pragma unroll
    for (int i = 0; i < 8; ++i) {
        const int rowb = m0 + i * 16 + quad * 4;
        float inv[4];
        #pragma unroll
        for (int r2 = 0; r2 < 4; ++r2) inv[r2] = 1.0f / rs[rowb + r2];
        #pragma unroll
        for (int j = 0; j < 4; ++j) {
            const int col = n0 + wv * 64 + j * 16 + l15;
            #pragma unroll
            for (int r2 = 0; r2 < 4; ++r2)
                C[(size_t)(rowb + r2) * 1024 + col] = acc[i][j][r2] * inv[r2];
        }
    }
}

extern "C" void kernel_launch(void* const* d_in, const int* in_sizes, int n_in,
                              void* d_out, int out_size, void* d_ws, size_t ws_size,
                              hipStream_t stream)
{
    const float* q  = (const float*)d_in[0];
    const float* k  = (const float*)d_in[1];
    const float* v  = (const float*)d_in[2];
    const float* Wq = (const float*)d_in[3];
    const float* bq = (const float*)d_in[4];
    const float* Wk = (const float*)d_in[5];
    const float* bk = (const float*)d_in[6];
    const float* Wv = (const float*)d_in[7];
    const float* bv = (const float*)d_in[8];
    float* out = (float*)d_out;

    const int Bn = 4, S = 2048;

    char* w = (char*)d_ws;
    unsigned short* Wt     = (unsigned short*)(w);                  // 6 MB
    unsigned short* Qp     = (unsigned short*)(w + (6u << 20));     // 16 MB [8192,1024]
    unsigned short* Kp     = (unsigned short*)(w + (22u << 20));    // 16 MB
    unsigned short* Vpt    = (unsigned short*)(w + (38u << 20));    // 16 MB [1024,8192]
    unsigned short* qkvbf  = (unsigned short*)(w + (54u << 20));    // 48 MB (dead after proj)
    unsigned short* Pexp   = (unsigned short*)(w + (54u << 20));    // 32 MB (over dead qkvbf)
    float*          rowsum = (float*)(w + (86u << 20));             // 32 KB

    // zero the row-sum accumulators (ws is poisoned before each call)
    hipMemsetAsync(rowsum, 0, (size_t)Bn * S * sizeof(float), stream);

    // prep: qkv fp32->bf16 + W->W^T bf16
    prep<<<dim3(27648), dim3(256), 0, stream>>>(q, k, v, Wq, Wk, Wv, qkvbf, Wt);

    // fused projections (4-wave 128x256, per-wave 128x64): -> Qp, Kp, Vpt^T
    proj8<<<dim3(768), dim3(256), 0, stream>>>(qkvbf, Wt, bq, bk, bv, Qp, Kp, Vpt);

    // Pexp = exp(Qp @ Kp^T / 32) bf16 + rowsum atomics
    scores8<<<dim3(512), dim3(256), 0, stream>>>(Qp, Kp, Pexp, rowsum);

    // out = (Pexp @ Vpt^T) / rowsum
    pv8<<<dim3(256), dim3(256), 0, stream>>>(Pexp, Vpt, rowsum, out);
}